// Round 5
// baseline (155.662 us; speedup 1.0000x reference)
//
#include <hip/hip_runtime.h>

// z(8,128,64,64) f32, codes(16,256,8) f32
// out: soft(8,64,64,128) | hard(8,64,64,128) | idx(8,64,64,16) as f32
#define NPOS 32768
#define CCH  128
#define LL   16
#define KK   256
#define CD   8

typedef float f32x2 __attribute__((ext_vector_type(2)));

#if __has_builtin(__builtin_amdgcn_exp2f)
#define EXP2F(x) __builtin_amdgcn_exp2f(x)
#else
#define EXP2F(x) __builtin_exp2f(x)
#endif

#define LOG2E 1.4426950408889634f   // scale h,c by LOG2E: exp2(-sqrt(d2')) == exp(-dist)
#define LN2   0.6931471805599453f   // un-scale acc (codes carry LOG2E)

// block: 256 threads = 2 latents x 128 lanes; each thread owns 4 positions.
// grid: 64 pos-chunks x 8 l-chunks = 512 blocks = 2 per CU.
__global__ __launch_bounds__(256, 2) void soft_hard_enc(
    const float* __restrict__ z, const float* __restrict__ codes,
    float* __restrict__ out)
{
    // per latent: 128 pairs x 16 floats [ (cs_e[c],cs_o[c]) c=0..7 ], cs = LOG2E*c
    __shared__ float s_codes[2 * 128 * 16];   // 16 KB

    const int tid = (int)threadIdx.x;
    const int bid = (int)blockIdx.x;
    const int posBase = (bid >> 3) * 512;
    const int lBase   = (bid & 7) * 2;

    // ---- stage codes: scaled + pair-interleaved (one 64B read/write per thread)
    {
        const int lt = tid >> 7;          // 0..1
        const int j  = tid & 127;         // pair index
        const float* g = codes + ((size_t)((lBase + lt) * KK + 2 * j)) * CD;
        float4 e0 = *(const float4*)(g);       // even code c0..c3
        float4 e1 = *(const float4*)(g + 4);   // even c4..c7
        float4 o0 = *(const float4*)(g + 8);   // odd  c0..c3
        float4 o1 = *(const float4*)(g + 12);  // odd  c4..c7
        float* d = s_codes + lt * (128 * 16) + j * 16;
        ((float4*)d)[0] = (float4){LOG2E*e0.x, LOG2E*o0.x, LOG2E*e0.y, LOG2E*o0.y};
        ((float4*)d)[1] = (float4){LOG2E*e0.z, LOG2E*o0.z, LOG2E*e0.w, LOG2E*o0.w};
        ((float4*)d)[2] = (float4){LOG2E*e1.x, LOG2E*o1.x, LOG2E*e1.y, LOG2E*o1.y};
        ((float4*)d)[3] = (float4){LOG2E*e1.z, LOG2E*o1.z, LOG2E*e1.w, LOG2E*o1.w};
    }

    const int l  = __builtin_amdgcn_readfirstlane(tid >> 7);  // wave-uniform
    const int p  = tid & 127;
    const int l4 = lBase + l;
    const int bb = posBase >> 12;            // 512-pos chunk never straddles a batch
    const int whBase = (posBase & 4095) + p;

    // hv: 4 positions x 8 channels, scaled; per-channel loads lane-coalesced
    const float* zb = z + (((size_t)(bb * CCH + l4 * CD)) << 12);
    f32x2 hs[4][CD];
#pragma unroll
    for (int i = 0; i < 4; ++i)
#pragma unroll
        for (int c = 0; c < CD; ++c) {
            float v = LOG2E * zb[(c << 12) + whBase + 128 * i];
            hs[i][c] = (f32x2){v, v};
        }

    __syncthreads();

    const float4* cb4 = (const float4*)(s_codes + l * (128 * 16));

    f32x2 acc[4][CD];
    f32x2 ssump[4];
    f32x2 bdp[4];
    int   bje[4], bjo[4];
#pragma unroll
    for (int i = 0; i < 4; ++i) {
#pragma unroll
        for (int c = 0; c < CD; ++c) acc[i][c] = (f32x2){0.f, 0.f};
        ssump[i] = (f32x2){0.f, 0.f};
        bdp[i]   = (f32x2){3.4e38f, 3.4e38f};
        bje[i] = 0; bjo[i] = 0;
    }

#pragma unroll 2
    for (int j = 0; j < KK / 2; ++j) {
        const float4* cp4 = cb4 + j * 4;     // wave-uniform -> LDS broadcast
        float4 q0 = cp4[0];
        float4 q1 = cp4[1];
        float4 q2 = cp4[2];
        float4 q3 = cp4[3];
        f32x2 cs[CD] = {
            {q0.x, q0.y}, {q0.z, q0.w}, {q1.x, q1.y}, {q1.z, q1.w},
            {q2.x, q2.y}, {q2.z, q2.w}, {q3.x, q3.y}, {q3.z, q3.w}};

#pragma unroll
        for (int i = 0; i < 4; ++i) {
            // direct squared distance: error ~eps*d2 -> argmin-safe (R0/R1 idx exact)
            f32x2 d2p = (f32x2){0.f, 0.f};
#pragma unroll
            for (int c = 0; c < CD; ++c) {
                f32x2 df = hs[i][c] - cs[c];
                d2p = __builtin_elementwise_fma(df, df, d2p);
            }
            float s0 = __builtin_amdgcn_sqrtf(d2p[0]);
            float s1 = __builtin_amdgcn_sqrtf(d2p[1]);
            f32x2 ep = (f32x2){EXP2F(-s0), EXP2F(-s1)};

            ssump[i] += ep;
#pragma unroll
            for (int c = 0; c < CD; ++c)
                acc[i][c] = __builtin_elementwise_fma(ep, cs[c], acc[i][c]);

            // strict < keeps first occurrence within parity (np.argmin)
            if (d2p[0] < bdp[i][0]) bje[i] = j;
            if (d2p[1] < bdp[i][1]) bjo[i] = j;
            bdp[i] = __builtin_elementwise_min(bdp[i], d2p);
        }
    }

    float* outh = out + (size_t)NPOS * CCH;
    float* outi = out + (size_t)2 * NPOS * CCH;

#pragma unroll
    for (int i = 0; i < 4; ++i) {
        const int pos = posBase + p + 128 * i;
        const float ssum = ssump[i][0] + ssump[i][1];
        const float sc   = LN2 / ssum;       // un-scale + softmax normalize

        float a[CD];
#pragma unroll
        for (int c = 0; c < CD; ++c) a[c] = (acc[i][c][0] + acc[i][c][1]) * sc;

        const size_t obase = (size_t)pos * CCH + (size_t)(l4 * CD);
        *(float4*)&out[obase]     = (float4){a[0], a[1], a[2], a[3]};
        *(float4*)&out[obase + 4] = (float4){a[4], a[5], a[6], a[7]};

        // merge parities; exact tie -> smaller k (first occurrence)
        const float bde = bdp[i][0], bdo = bdp[i][1];
        int bk = 2 * bje[i];
        if (bdo < bde || (bdo == bde && bjo[i] < bje[i])) bk = 2 * bjo[i] + 1;

        const float* hp = codes + ((size_t)(l4 * KK + bk)) * CD;  // L2-hot gather
        float4 h0 = *(const float4*)(hp);
        float4 h1 = *(const float4*)(hp + 4);
        *(float4*)&outh[obase]     = h0;
        *(float4*)&outh[obase + 4] = h1;

        outi[(size_t)pos * LL + l4] = (float)bk;
    }
}

extern "C" void kernel_launch(void* const* d_in, const int* in_sizes, int n_in,
                              void* d_out, int out_size, void* d_ws, size_t ws_size,
                              hipStream_t stream) {
    const float* z     = (const float*)d_in[0];
    const float* codes = (const float*)d_in[1];
    float* out = (float*)d_out;
    soft_hard_enc<<<dim3(512), dim3(256), 0, stream>>>(z, codes, out);
}